// Round 10
// baseline (579.147 us; speedup 1.0000x reference)
//
#include <hip/hip_runtime.h>

constexpr int NN = 50000;     // nodes
constexpr int NE = 800000;    // edges
constexpr float SLOPE_A = 0.2f;   // attention leaky_relu
constexpr float SLOPE_R = 0.01f;  // activation leaky_relu
constexpr int SCB = 196;      // scan blocks: 196*256 = 50176 >= NN

typedef __attribute__((ext_vector_type(8))) short bf16x8;
typedef __attribute__((ext_vector_type(4))) float f32x4;

__device__ __forceinline__ unsigned short f2bf(float f) {
    union { float f; unsigned u; } v; v.f = f;
    unsigned u = v.u;
    unsigned r = u + 0x7fffu + ((u >> 16) & 1u);  // round-to-nearest-even
    return (unsigned short)(r >> 16);
}
__device__ __forceinline__ float bf2f(unsigned short s) {
    union { unsigned u; float f; } v; v.u = ((unsigned)s) << 16;
    return v.f;
}

// ---------------- CSR build ----------------
__global__ void k_hist(const int* __restrict__ dst, int* __restrict__ cnt) {
    int i = blockIdx.x * 256 + threadIdx.x;
    if (i < NE) atomicAdd(&cnt[dst[i]], 1);
}

__global__ void k_scan1(const int* __restrict__ cnt, int* __restrict__ loc,
                        int* __restrict__ bsum) {
    __shared__ int sh[256];
    int t = threadIdx.x;
    int i = blockIdx.x * 256 + t;
    int v = (i < NN) ? cnt[i] : 0;
    sh[t] = v;
    __syncthreads();
    for (int off = 1; off < 256; off <<= 1) {
        int tmp = (t >= off) ? sh[t - off] : 0;
        __syncthreads();
        sh[t] += tmp;
        __syncthreads();
    }
    loc[i] = sh[t] - v;
    if (t == 255) bsum[blockIdx.x] = sh[255];
}

__global__ void k_scan2(const int* __restrict__ bsum, int* __restrict__ boff,
                        int* __restrict__ rowptr) {
    __shared__ int sh[256];
    int t = threadIdx.x;
    int v = (t < SCB) ? bsum[t] : 0;
    sh[t] = v;
    __syncthreads();
    for (int off = 1; off < 256; off <<= 1) {
        int tmp = (t >= off) ? sh[t - off] : 0;
        __syncthreads();
        sh[t] += tmp;
        __syncthreads();
    }
    if (t < SCB) boff[t] = sh[t] - v;
    if (t == 255) rowptr[NN] = sh[255];
}

__global__ void k_scan3(const int* __restrict__ loc, const int* __restrict__ boff,
                        int* __restrict__ rowptr, int* __restrict__ cursor) {
    int i = blockIdx.x * 256 + threadIdx.x;
    if (i < NN) {
        int r = loc[i] + boff[blockIdx.x];
        rowptr[i] = r;
        cursor[i] = r;
    }
}

__global__ void k_scatter(const int* __restrict__ src, const int* __restrict__ dst,
                          int* __restrict__ cursor, int* __restrict__ ssrc) {
    int i = blockIdx.x * 256 + threadIdx.x;
    if (i < NE) {
        int d = dst[i];
        int pos = atomicAdd(&cursor[d], 1);
        ssrc[pos] = src[i];
    }
}

// ---------------- fold: Wfrag + cvec + wl/wr fragment + offlr, all from fp32 W ----
// has_bn=1 grid 296: b<32 Wfrag | 32..287 cvec | 288..295 lr-fold (n=b-288)
// has_bn=0 grid  40: b<32 Wfrag | 32..39 lr-fold (n=b-32)
__global__ void k_fold(const float* __restrict__ W, const float* __restrict__ sc,
                       const float* __restrict__ sh, const float* __restrict__ al,
                       const float* __restrict__ ar, unsigned short* __restrict__ Wfrag,
                       float* __restrict__ cvec, unsigned short* __restrict__ wlrfrag,
                       float* __restrict__ offlr, int has_bn) {
    int b = blockIdx.x;
    if (b < 32) {
        int gid = b * 256 + threadIdx.x;   // < 8192; one thread = 8 shorts
        int lane = gid & 63;
        int frag = gid >> 6;               // 0..127
        int j = frag & 3, kc = (frag >> 2) & 7, w = frag >> 5;
        int mm = lane & 15, q = lane >> 4;
        int n = 64 * w + 16 * j + mm;
        int k0 = kc * 32 + q * 8;
        unsigned short o[8];
#pragma unroll
        for (int t = 0; t < 8; t++) {
            float wv = W[(size_t)(k0 + t) * 256 + n];
            if (sc) wv *= sc[k0 + t];
            o[t] = f2bf(wv);
        }
        *(uint4*)(Wfrag + (size_t)gid * 8) = *(const uint4*)o;
    } else if (has_bn && b < 288) {
        __shared__ float red[256];
        int n = b - 32, k = threadIdx.x;
        red[k] = sh[k] * W[(size_t)k * 256 + n];
        __syncthreads();
        for (int off = 128; off > 0; off >>= 1) {
            if (k < off) red[k] += red[k + off];
            __syncthreads();
        }
        if (k == 0) cvec[n] = red[0];
    } else {
        int n = b - (has_bn ? 288 : 32);   // 0..7
        int h = n >> 1;
        const float* a = (n & 1) ? ar : al;
        int k = threadIdx.x;
        float raw = 0.f;
#pragma unroll 8
        for (int d = 0; d < 64; d++)
            raw += W[(size_t)k * 256 + 64 * h + d] * a[h * 64 + d];
        float val = (sc ? sc[k] : 1.f) * raw;
        int kc = k >> 5, rem = k & 31, q = rem >> 3, t = rem & 7;  // k = kc*32+q*8+t
        wlrfrag[kc * 512 + (q * 16 + n) * 8 + t] = f2bf(val);
        wlrfrag[kc * 512 + (q * 16 + n + 8) * 8 + t] = 0;   // zero the unused col
        __shared__ float red[256];
        red[k] = sh ? sh[k] * raw : 0.f;
        __syncthreads();
        for (int off = 128; off > 0; off >>= 1) {
            if (k < off) red[k] += red[k + off];
            __syncthreads();
        }
        if (k == 0) offlr[n] = red[0];
    }
}

// ---------------- GEMM: feat = A @ Wfrag (+cvec); el/er via extra MFMA --------
// block: 256 thr = 4 waves; tile 64 rows x 256 cols; wave w owns cols [64w,64w+64).
// Wave 0 additionally computes the 8-col el/er matvec with one extra B-frag.
// NOTE: no min-occupancy bound -- acc(64)+accLR(16)+frags need ~160 VGPR; a
// (256,2) bound caps at 128 and forces accumulator spills.
__launch_bounds__(256)
__global__ void k_gemm(const void* __restrict__ Araw, int af32,
                       const unsigned short* __restrict__ Wfrag,
                       const float* __restrict__ cvec,
                       const unsigned short* __restrict__ wlrfrag,
                       const float* __restrict__ offlr,
                       unsigned short* __restrict__ feat16, float* __restrict__ el,
                       float* __restrict__ er) {
    constexpr int AP = 264;  // A lds pitch in bf16 elems (row start 16B-aligned)
    __shared__ __align__(16) unsigned short Alds[64 * AP];
    const int tid = threadIdx.x;
    const int rowbase = blockIdx.x * 64;

    // stage A: 64 rows x 256 bf16
    if (af32) {
        const float* A = (const float*)Araw;
        int r = tid >> 6;
        int c4 = tid & 63;
        for (int it = 0; it < 16; it++) {
            int rr = it * 4 + r;
            int gr = rowbase + rr;
            float4 v = make_float4(0.f, 0.f, 0.f, 0.f);
            if (gr < NN) v = *(const float4*)(A + (size_t)gr * 256 + c4 * 4);
            ushort4 pv;
            pv.x = f2bf(v.x); pv.y = f2bf(v.y); pv.z = f2bf(v.z); pv.w = f2bf(v.w);
            *(ushort4*)(&Alds[rr * AP + c4 * 4]) = pv;
        }
    } else {
        const unsigned short* A = (const unsigned short*)Araw;
        for (int it = 0; it < 8; it++) {
            int idx = it * 256 + tid;
            int rr = idx >> 5;
            int c16 = idx & 31;
            int gr = rowbase + rr;
            uint4 v = make_uint4(0u, 0u, 0u, 0u);
            if (gr < NN) v = *(const uint4*)(A + (size_t)gr * 256 + c16 * 8);
            *(uint4*)(&Alds[rr * AP + c16 * 8]) = v;
        }
    }
    __syncthreads();

    f32x4 acc[4][4];
    for (int i = 0; i < 4; i++)
        for (int j = 0; j < 4; j++)
            acc[i][j] = (f32x4){0.f, 0.f, 0.f, 0.f};
    f32x4 accLR[4];
    for (int i = 0; i < 4; i++) accLR[i] = (f32x4){0.f, 0.f, 0.f, 0.f};

    const int lane = tid & 63, w = tid >> 6;
    const int mm = lane & 15, q = lane >> 4;

    const unsigned short* bbase = Wfrag + ((size_t)w * 8 * 4) * 512 + (size_t)lane * 8;

#pragma unroll
    for (int kc = 0; kc < 8; kc++) {
        bf16x8 a[4], b[4];
        for (int i = 0; i < 4; i++)
            a[i] = *(const bf16x8*)(&Alds[(16 * i + mm) * AP + kc * 32 + q * 8]);
        for (int j = 0; j < 4; j++)
            b[j] = *(const bf16x8*)(bbase + (size_t)(kc * 4 + j) * 512);
        for (int i = 0; i < 4; i++)
            for (int j = 0; j < 4; j++)
                acc[i][j] = __builtin_amdgcn_mfma_f32_16x16x32_bf16(a[i], b[j], acc[i][j], 0, 0, 0);
        if (w == 0) {
            bf16x8 blr = *(const bf16x8*)(wlrfrag + kc * 512 + lane * 8);
            for (int i = 0; i < 4; i++)
                accLR[i] = __builtin_amdgcn_mfma_f32_16x16x32_bf16(a[i], blr, accLR[i], 0, 0, 0);
        }
    }
    __syncthreads();   // all waves done reading Alds before epilogue reuses it

    // ---- folded-BN column offset on feat ----
    if (cvec) {
        float cv[4];
        for (int j = 0; j < 4; j++) cv[j] = cvec[64 * w + 16 * j + mm];
        for (int i = 0; i < 4; i++)
            for (int j = 0; j < 4; j++)
                for (int r = 0; r < 4; r++)
                    acc[i][j][r] += cv[j];
    }

    // ---- el/er write (wave 0, C-layout col=mm -> n=2h+s) ----
    if (w == 0 && mm < 8) {
        float off = offlr[mm];
        int h = mm >> 1;
        float* dstp = (mm & 1) ? er : el;
        for (int i = 0; i < 4; i++)
            for (int r = 0; r < 4; r++) {
                int gr = rowbase + 16 * i + q * 4 + r;
                if (gr < NN) dstp[gr * 4 + h] = accLR[i][r] + off;
            }
    }

    // ---- LDS-bounce feat16 store (C/D layout: col=lane&15, row=(lane>>4)*4+reg) ----
    for (int i = 0; i < 4; i++)
        for (int j = 0; j < 4; j++) {
            int gc = 64 * w + 16 * j + mm;
            for (int r = 0; r < 4; r++) {
                int rr = 16 * i + q * 4 + r;
                Alds[rr * AP + gc] = f2bf(acc[i][j][r]);
            }
        }
    __syncthreads();
    for (int it = 0; it < 8; it++) {
        int idx = it * 256 + tid;
        int rr = idx >> 5;
        int c16 = idx & 31;
        int gr = rowbase + rr;
        if (gr < NN)
            *(uint4*)(feat16 + (size_t)gr * 256 + c16 * 8) = *(const uint4*)(&Alds[rr * AP + c16 * 8]);
    }
}

// ---------------- per-dst softmax + weighted aggregation (bf16 gather) ----------------
// ONE wave per destination node; lane l owns channels [4l,4l+4); head h = l>>4.
// No-max softmax (scores bounded). Predicated unroll-8: best measured point
// (unroll-16 raises VGPR 24->40, occupancy 67->50%, net -3%).
__launch_bounds__(256)
__global__ void k_agg(const unsigned short* __restrict__ feat16, const float* __restrict__ el,
                      const float* __restrict__ er, const int* __restrict__ rowptr,
                      const int* __restrict__ ssrc,
                      const unsigned short* __restrict__ residh, const float* __restrict__ residf,
                      const float* __restrict__ bnscale, const float* __restrict__ bnshift,
                      int use_bn, const float* __restrict__ bias, int act,
                      unsigned short* __restrict__ outh, float* __restrict__ outf,
                      int final_mean) {
    int n = __builtin_amdgcn_readfirstlane(blockIdx.x * 4 + (threadIdx.x >> 6));
    int l = threadIdx.x & 63;
    int h = l >> 4;
    int beg = rowptr[n], end = rowptr[n + 1];
    float erh = er[n * 4 + h];

    float d = 0.f;
    float4 acc = make_float4(0.f, 0.f, 0.f, 0.f);

    for (int e = beg; e < end; e += 8) {
        int ss[8];
        float cc[8];
        ushort4 ff[8];
#pragma unroll
        for (int j = 0; j < 8; j++) {
            int ee = e + j;
            ss[j] = ssrc[(ee < end) ? ee : beg];
        }
#pragma unroll
        for (int j = 0; j < 8; j++)
            cc[j] = el[ss[j] * 4 + h];
#pragma unroll
        for (int j = 0; j < 8; j++)
            ff[j] = *(const ushort4*)(feat16 + (size_t)ss[j] * 256 + l * 4);
#pragma unroll
        for (int j = 0; j < 8; j++) {
            float sc = cc[j] + erh;
            sc = (sc > 0.f) ? sc : SLOPE_A * sc;
            float wgt = ((e + j) < end) ? __expf(sc) : 0.f;
            d += wgt;
            acc.x += bf2f(ff[j].x) * wgt;
            acc.y += bf2f(ff[j].y) * wgt;
            acc.z += bf2f(ff[j].z) * wgt;
            acc.w += bf2f(ff[j].w) * wgt;
        }
    }

    float invd = 1.f / fmaxf(d, 1e-9f);
    acc.x *= invd; acc.y *= invd; acc.z *= invd; acc.w *= invd;

    // residual (+BN) + bias
    float4 r;
    if (residf) {
        r = *(const float4*)(residf + (size_t)n * 256 + l * 4);
    } else {
        ushort4 rv = *(const ushort4*)(residh + (size_t)n * 256 + l * 4);
        r = make_float4(bf2f(rv.x), bf2f(rv.y), bf2f(rv.z), bf2f(rv.w));
    }
    if (use_bn) {
        float4 sc4 = *(const float4*)(bnscale + l * 4);
        float4 sh4 = *(const float4*)(bnshift + l * 4);
        r.x = r.x * sc4.x + sh4.x;
        r.y = r.y * sc4.y + sh4.y;
        r.z = r.z * sc4.z + sh4.z;
        r.w = r.w * sc4.w + sh4.w;
    }
    float4 bb = *(const float4*)(bias + l * 4);
    acc.x += r.x + bb.x; acc.y += r.y + bb.y;
    acc.z += r.z + bb.z; acc.w += r.w + bb.w;
    if (act) {
        acc.x = (acc.x > 0.f) ? acc.x : SLOPE_R * acc.x;
        acc.y = (acc.y > 0.f) ? acc.y : SLOPE_R * acc.y;
        acc.z = (acc.z > 0.f) ? acc.z : SLOPE_R * acc.z;
        acc.w = (acc.w > 0.f) ? acc.w : SLOPE_R * acc.w;
    }

    if (!final_mean) {
        ushort4 p;
        p.x = f2bf(acc.x); p.y = f2bf(acc.y); p.z = f2bf(acc.z); p.w = f2bf(acc.w);
        *(ushort4*)(outh + (size_t)n * 256 + l * 4) = p;
    } else {
        acc.x += __shfl_xor(acc.x, 16, 64); acc.x += __shfl_xor(acc.x, 32, 64);
        acc.y += __shfl_xor(acc.y, 16, 64); acc.y += __shfl_xor(acc.y, 32, 64);
        acc.z += __shfl_xor(acc.z, 16, 64); acc.z += __shfl_xor(acc.z, 32, 64);
        acc.w += __shfl_xor(acc.w, 16, 64); acc.w += __shfl_xor(acc.w, 32, 64);
        if (l < 16) {
            acc.x *= 0.25f; acc.y *= 0.25f; acc.z *= 0.25f; acc.w *= 0.25f;
            *(float4*)(outf + (size_t)n * 64 + l * 4) = acc;
        }
    }
}

// ---------------- BatchNorm stats: vectorized partials, no atomics ----------------
// grid 64: each block covers 784 rows; bnfinal then reduces only 64 partials.
__global__ void k_bnstats(const unsigned short* __restrict__ hh, float* __restrict__ pbuf) {
    __shared__ float ps[8 * 256];
    __shared__ float ps2[8 * 256];
    int t = threadIdx.x, b = blockIdx.x;
    int r8 = t >> 5, c32 = t & 31;
    int r0 = b * 784, r1 = min(r0 + 784, NN);
    float s[8], s2[8];
#pragma unroll
    for (int e = 0; e < 8; e++) { s[e] = 0.f; s2[e] = 0.f; }
    for (int r = r0 + r8; r < r1; r += 8) {
        uint4 v = *(const uint4*)(hh + (size_t)r * 256 + c32 * 8);
        const unsigned short* pv = (const unsigned short*)&v;
#pragma unroll
        for (int e = 0; e < 8; e++) {
            float f = bf2f(pv[e]);
            s[e] += f; s2[e] += f * f;
        }
    }
#pragma unroll
    for (int e = 0; e < 8; e++) {
        ps[r8 * 256 + c32 * 8 + e] = s[e];
        ps2[r8 * 256 + c32 * 8 + e] = s2[e];
    }
    __syncthreads();
    float ts = 0.f, ts2 = 0.f;
    for (int g = 0; g < 8; g++) { ts += ps[g * 256 + t]; ts2 += ps2[g * 256 + t]; }
    pbuf[b * 512 + t] = ts;
    pbuf[b * 512 + 256 + t] = ts2;
}

__global__ void k_bnfinal(const float* __restrict__ pbuf, const float* __restrict__ g,
                          const float* __restrict__ be, float* __restrict__ scale,
                          float* __restrict__ shift) {
    int t = threadIdx.x;
    float s = 0.f, s2 = 0.f;
    for (int b = 0; b < 64; b++) {
        s += pbuf[b * 512 + t];
        s2 += pbuf[b * 512 + 256 + t];
    }
    float mu = s * (1.f / NN);
    float var = s2 * (1.f / NN) - mu * mu;
    float rs = rsqrtf(var + 1e-5f);
    float sc = rs * g[t];
    scale[t] = sc;
    shift[t] = be[t] - mu * sc;
}

// ---------------- launcher ----------------
extern "C" void kernel_launch(void* const* d_in, const int* in_sizes, int n_in,
                              void* d_out, int out_size, void* d_ws, size_t ws_size,
                              hipStream_t stream) {
    const float* x   = (const float*)d_in[0];
    const int* src   = (const int*)d_in[1];
    const int* dst   = (const int*)d_in[2];
    const float* W1  = (const float*)d_in[3];
    const float* al1 = (const float*)d_in[4];
    const float* ar1 = (const float*)d_in[5];
    const float* b1  = (const float*)d_in[6];
    const float* W2  = (const float*)d_in[7];
    const float* al2 = (const float*)d_in[8];
    const float* ar2 = (const float*)d_in[9];
    const float* b2  = (const float*)d_in[10];
    const float* W3  = (const float*)d_in[11];
    const float* al3 = (const float*)d_in[12];
    const float* ar3 = (const float*)d_in[13];
    const float* b3  = (const float*)d_in[14];
    const float* g1  = (const float*)d_in[15];
    const float* be1 = (const float*)d_in[16];
    const float* g2  = (const float*)d_in[17];
    const float* be2 = (const float*)d_in[18];
    float* out = (float*)d_out;

    char* ws = (char*)d_ws;
    size_t off = 0;
    auto alloc = [&](size_t bytes) {
        void* p = ws + off;
        off += (bytes + 255) & ~(size_t)255;
        return p;
    };
    int* rowptr = (int*)alloc((NN + 1) * sizeof(int));
    int* cursor = (int*)alloc(NN * sizeof(int));
    int* cnt    = (int*)alloc(SCB * 256 * sizeof(int));
    int* loc    = (int*)alloc(SCB * 256 * sizeof(int));
    int* bsum   = (int*)alloc(SCB * sizeof(int));
    int* boff   = (int*)alloc(SCB * sizeof(int));
    int* ssrc   = (int*)alloc(NE * sizeof(int));
    unsigned short* feat16 = (unsigned short*)alloc((size_t)NN * 256 * sizeof(unsigned short));
    unsigned short* hbuf   = (unsigned short*)alloc((size_t)NN * 256 * sizeof(unsigned short));
    float* el   = (float*)alloc((size_t)NN * 4 * sizeof(float));
    float* er   = (float*)alloc((size_t)NN * 4 * sizeof(float));
    unsigned short* Wfrag1  = (unsigned short*)alloc(65536 * sizeof(unsigned short));
    unsigned short* Wfrag2  = (unsigned short*)alloc(65536 * sizeof(unsigned short));
    unsigned short* wlrfrag = (unsigned short*)alloc(4096 * sizeof(unsigned short));
    float* offlr   = (float*)alloc(16 * sizeof(float));
    float* cvec    = (float*)alloc(256 * sizeof(float));
    float* pbuf    = (float*)alloc(64 * 512 * sizeof(float));
    float* bnscale = (float*)alloc(256 * sizeof(float));
    float* bnshift = (float*)alloc(256 * sizeof(float));

    // CSR build (graph identical for all layers)
    hipMemsetAsync(cnt, 0, NN * sizeof(int), stream);
    k_hist<<<(NE + 255) / 256, 256, 0, stream>>>(dst, cnt);
    k_scan1<<<SCB, 256, 0, stream>>>(cnt, loc, bsum);
    k_scan2<<<1, 256, 0, stream>>>(bsum, boff, rowptr);
    k_scan3<<<SCB, 256, 0, stream>>>(loc, boff, rowptr, cursor);
    k_scatter<<<(NE + 255) / 256, 256, 0, stream>>>(src, dst, cursor, ssrc);
    k_fold<<<40, 256, 0, stream>>>(W1, nullptr, nullptr, al1, ar1,
                                   Wfrag1, nullptr, wlrfrag, offlr, 0);

    const int GB = (NN + 63) / 64;  // 782
    const int NB = NN / 4;          // 12500

    // ---- layer 1 ----
    k_gemm<<<GB, 256, 0, stream>>>(x, 1, Wfrag1, nullptr, wlrfrag, offlr, feat16, el, er);
    k_agg<<<NB, 256, 0, stream>>>(feat16, el, er, rowptr, ssrc, nullptr, x,
                                  nullptr, nullptr, 0, b1, 1, hbuf, nullptr, 0);
    k_bnstats<<<64, 256, 0, stream>>>(hbuf, pbuf);
    k_bnfinal<<<1, 256, 0, stream>>>(pbuf, g1, be1, bnscale, bnshift);
    k_fold<<<296, 256, 0, stream>>>(W2, bnscale, bnshift, al2, ar2,
                                    Wfrag2, cvec, wlrfrag, offlr, 1);

    // ---- layer 2 ----
    k_gemm<<<GB, 256, 0, stream>>>(hbuf, 0, Wfrag2, cvec, wlrfrag, offlr, feat16, el, er);
    k_agg<<<NB, 256, 0, stream>>>(feat16, el, er, rowptr, ssrc, hbuf, nullptr,
                                  bnscale, bnshift, 1, b2, 1, hbuf, nullptr, 0);
    k_bnstats<<<64, 256, 0, stream>>>(hbuf, pbuf);
    k_bnfinal<<<1, 256, 0, stream>>>(pbuf, g2, be2, bnscale, bnshift);
    k_fold<<<296, 256, 0, stream>>>(W3, bnscale, bnshift, al3, ar3,
                                    Wfrag2, cvec, wlrfrag, offlr, 1);

    // ---- layer 3 ----
    k_gemm<<<GB, 256, 0, stream>>>(hbuf, 0, Wfrag2, cvec, wlrfrag, offlr, feat16, el, er);
    k_agg<<<NB, 256, 0, stream>>>(feat16, el, er, rowptr, ssrc, hbuf, nullptr,
                                  bnscale, bnshift, 1, b3, 0, nullptr, out, 1);
}

// Round 11
// 545.440 us; speedup vs baseline: 1.0618x; 1.0618x over previous
//
#include <hip/hip_runtime.h>

constexpr int NN = 50000;     // nodes
constexpr int NE = 800000;    // edges
constexpr float SLOPE_A = 0.2f;   // attention leaky_relu
constexpr float SLOPE_R = 0.01f;  // activation leaky_relu
constexpr int SCB = 196;      // scan blocks: 196*256 = 50176 >= NN

typedef __attribute__((ext_vector_type(8))) short bf16x8;
typedef __attribute__((ext_vector_type(4))) float f32x4;

__device__ __forceinline__ unsigned short f2bf(float f) {
    union { float f; unsigned u; } v; v.f = f;
    unsigned u = v.u;
    unsigned r = u + 0x7fffu + ((u >> 16) & 1u);  // round-to-nearest-even
    return (unsigned short)(r >> 16);
}
__device__ __forceinline__ float bf2f(unsigned short s) {
    union { unsigned u; float f; } v; v.u = ((unsigned)s) << 16;
    return v.f;
}

// ---------------- CSR build ----------------
__global__ void k_hist(const int* __restrict__ dst, int* __restrict__ cnt) {
    int i = blockIdx.x * 256 + threadIdx.x;
    if (i < NE) atomicAdd(&cnt[dst[i]], 1);
}

__global__ void k_scan1(const int* __restrict__ cnt, int* __restrict__ loc,
                        int* __restrict__ bsum) {
    __shared__ int sh[256];
    int t = threadIdx.x;
    int i = blockIdx.x * 256 + t;
    int v = (i < NN) ? cnt[i] : 0;
    sh[t] = v;
    __syncthreads();
    for (int off = 1; off < 256; off <<= 1) {
        int tmp = (t >= off) ? sh[t - off] : 0;
        __syncthreads();
        sh[t] += tmp;
        __syncthreads();
    }
    loc[i] = sh[t] - v;
    if (t == 255) bsum[blockIdx.x] = sh[255];
}

__global__ void k_scan2(const int* __restrict__ bsum, int* __restrict__ boff,
                        int* __restrict__ rowptr) {
    __shared__ int sh[256];
    int t = threadIdx.x;
    int v = (t < SCB) ? bsum[t] : 0;
    sh[t] = v;
    __syncthreads();
    for (int off = 1; off < 256; off <<= 1) {
        int tmp = (t >= off) ? sh[t - off] : 0;
        __syncthreads();
        sh[t] += tmp;
        __syncthreads();
    }
    if (t < SCB) boff[t] = sh[t] - v;
    if (t == 255) rowptr[NN] = sh[255];
}

__global__ void k_scan3(const int* __restrict__ loc, const int* __restrict__ boff,
                        int* __restrict__ rowptr, int* __restrict__ cursor) {
    int i = blockIdx.x * 256 + threadIdx.x;
    if (i < NN) {
        int r = loc[i] + boff[blockIdx.x];
        rowptr[i] = r;
        cursor[i] = r;
    }
}

__global__ void k_scatter(const int* __restrict__ src, const int* __restrict__ dst,
                          int* __restrict__ cursor, int* __restrict__ ssrc) {
    int i = blockIdx.x * 256 + threadIdx.x;
    if (i < NE) {
        int d = dst[i];
        int pos = atomicAdd(&cursor[d], 1);
        ssrc[pos] = src[i];
    }
}

// ---------------- fold: Wfrag + cvec + wl/wr fragment + offlr, all from fp32 W ----
// has_bn=1 grid 296: b<32 Wfrag | 32..287 cvec | 288..295 lr-fold (n=b-288)
// has_bn=0 grid  40: b<32 Wfrag | 32..39 lr-fold (n=b-32)
__global__ void k_fold(const float* __restrict__ W, const float* __restrict__ sc,
                       const float* __restrict__ sh, const float* __restrict__ al,
                       const float* __restrict__ ar, unsigned short* __restrict__ Wfrag,
                       float* __restrict__ cvec, unsigned short* __restrict__ wlrfrag,
                       float* __restrict__ offlr, int has_bn) {
    int b = blockIdx.x;
    if (b < 32) {
        int gid = b * 256 + threadIdx.x;   // < 8192; one thread = 8 shorts
        int lane = gid & 63;
        int frag = gid >> 6;               // 0..127
        int j = frag & 3, kc = (frag >> 2) & 7, w = frag >> 5;
        int mm = lane & 15, q = lane >> 4;
        int n = 64 * w + 16 * j + mm;
        int k0 = kc * 32 + q * 8;
        unsigned short o[8];
#pragma unroll
        for (int t = 0; t < 8; t++) {
            float wv = W[(size_t)(k0 + t) * 256 + n];
            if (sc) wv *= sc[k0 + t];
            o[t] = f2bf(wv);
        }
        *(uint4*)(Wfrag + (size_t)gid * 8) = *(const uint4*)o;
    } else if (has_bn && b < 288) {
        __shared__ float red[256];
        int n = b - 32, k = threadIdx.x;
        red[k] = sh[k] * W[(size_t)k * 256 + n];
        __syncthreads();
        for (int off = 128; off > 0; off >>= 1) {
            if (k < off) red[k] += red[k + off];
            __syncthreads();
        }
        if (k == 0) cvec[n] = red[0];
    } else {
        int n = b - (has_bn ? 288 : 32);   // 0..7
        int h = n >> 1;
        const float* a = (n & 1) ? ar : al;
        int k = threadIdx.x;
        float raw = 0.f;
#pragma unroll 8
        for (int d = 0; d < 64; d++)
            raw += W[(size_t)k * 256 + 64 * h + d] * a[h * 64 + d];
        float val = (sc ? sc[k] : 1.f) * raw;
        int kc = k >> 5, rem = k & 31, q = rem >> 3, t = rem & 7;  // k = kc*32+q*8+t
        wlrfrag[kc * 512 + (q * 16 + n) * 8 + t] = f2bf(val);
        wlrfrag[kc * 512 + (q * 16 + n + 8) * 8 + t] = 0;   // zero the unused col
        __shared__ float red[256];
        red[k] = sh ? sh[k] * raw : 0.f;
        __syncthreads();
        for (int off = 128; off > 0; off >>= 1) {
            if (k < off) red[k] += red[k + off];
            __syncthreads();
        }
        if (k == 0) offlr[n] = red[0];
    }
}

// ---------------- GEMM: feat = A @ Wfrag (+cvec); el/er via extra MFMA --------
// block: 256 thr = 4 waves; tile 64 rows x 256 cols; wave w owns cols [64w,64w+64).
// Wave 0 additionally computes the 8-col el/er matvec with one extra B-frag.
__launch_bounds__(256)
__global__ void k_gemm(const void* __restrict__ Araw, int af32,
                       const unsigned short* __restrict__ Wfrag,
                       const float* __restrict__ cvec,
                       const unsigned short* __restrict__ wlrfrag,
                       const float* __restrict__ offlr,
                       unsigned short* __restrict__ feat16, float* __restrict__ el,
                       float* __restrict__ er) {
    constexpr int AP = 264;  // A lds pitch in bf16 elems (row start 16B-aligned)
    __shared__ __align__(16) unsigned short Alds[64 * AP];
    const int tid = threadIdx.x;
    const int rowbase = blockIdx.x * 64;

    // stage A: 64 rows x 256 bf16
    if (af32) {
        const float* A = (const float*)Araw;
        int r = tid >> 6;
        int c4 = tid & 63;
        for (int it = 0; it < 16; it++) {
            int rr = it * 4 + r;
            int gr = rowbase + rr;
            float4 v = make_float4(0.f, 0.f, 0.f, 0.f);
            if (gr < NN) v = *(const float4*)(A + (size_t)gr * 256 + c4 * 4);
            ushort4 pv;
            pv.x = f2bf(v.x); pv.y = f2bf(v.y); pv.z = f2bf(v.z); pv.w = f2bf(v.w);
            *(ushort4*)(&Alds[rr * AP + c4 * 4]) = pv;
        }
    } else {
        const unsigned short* A = (const unsigned short*)Araw;
        for (int it = 0; it < 8; it++) {
            int idx = it * 256 + tid;
            int rr = idx >> 5;
            int c16 = idx & 31;
            int gr = rowbase + rr;
            uint4 v = make_uint4(0u, 0u, 0u, 0u);
            if (gr < NN) v = *(const uint4*)(A + (size_t)gr * 256 + c16 * 8);
            *(uint4*)(&Alds[rr * AP + c16 * 8]) = v;
        }
    }
    __syncthreads();

    f32x4 acc[4][4];
    for (int i = 0; i < 4; i++)
        for (int j = 0; j < 4; j++)
            acc[i][j] = (f32x4){0.f, 0.f, 0.f, 0.f};
    f32x4 accLR[4];
    for (int i = 0; i < 4; i++) accLR[i] = (f32x4){0.f, 0.f, 0.f, 0.f};

    const int lane = tid & 63, w = tid >> 6;
    const int mm = lane & 15, q = lane >> 4;

    const unsigned short* bbase = Wfrag + ((size_t)w * 8 * 4) * 512 + (size_t)lane * 8;

#pragma unroll
    for (int kc = 0; kc < 8; kc++) {
        bf16x8 a[4], b[4];
        for (int i = 0; i < 4; i++)
            a[i] = *(const bf16x8*)(&Alds[(16 * i + mm) * AP + kc * 32 + q * 8]);
        for (int j = 0; j < 4; j++)
            b[j] = *(const bf16x8*)(bbase + (size_t)(kc * 4 + j) * 512);
        for (int i = 0; i < 4; i++)
            for (int j = 0; j < 4; j++)
                acc[i][j] = __builtin_amdgcn_mfma_f32_16x16x32_bf16(a[i], b[j], acc[i][j], 0, 0, 0);
        if (w == 0) {
            bf16x8 blr = *(const bf16x8*)(wlrfrag + kc * 512 + lane * 8);
            for (int i = 0; i < 4; i++)
                accLR[i] = __builtin_amdgcn_mfma_f32_16x16x32_bf16(a[i], blr, accLR[i], 0, 0, 0);
        }
    }
    __syncthreads();   // all waves done reading Alds before epilogue reuses it

    // ---- folded-BN column offset on feat ----
    if (cvec) {
        float cv[4];
        for (int j = 0; j < 4; j++) cv[j] = cvec[64 * w + 16 * j + mm];
        for (int i = 0; i < 4; i++)
            for (int j = 0; j < 4; j++)
                for (int r = 0; r < 4; r++)
                    acc[i][j][r] += cv[j];
    }

    // ---- el/er write (wave 0, C-layout col=mm -> n=2h+s) ----
    if (w == 0 && mm < 8) {
        float off = offlr[mm];
        int h = mm >> 1;
        float* dstp = (mm & 1) ? er : el;
        for (int i = 0; i < 4; i++)
            for (int r = 0; r < 4; r++) {
                int gr = rowbase + 16 * i + q * 4 + r;
                if (gr < NN) dstp[gr * 4 + h] = accLR[i][r] + off;
            }
    }

    // ---- LDS-bounce feat16 store (C/D layout: col=lane&15, row=(lane>>4)*4+reg) ----
    for (int i = 0; i < 4; i++)
        for (int j = 0; j < 4; j++) {
            int gc = 64 * w + 16 * j + mm;
            for (int r = 0; r < 4; r++) {
                int rr = 16 * i + q * 4 + r;
                Alds[rr * AP + gc] = f2bf(acc[i][j][r]);
            }
        }
    __syncthreads();
    for (int it = 0; it < 8; it++) {
        int idx = it * 256 + tid;
        int rr = idx >> 5;
        int c16 = idx & 31;
        int gr = rowbase + rr;
        if (gr < NN)
            *(uint4*)(feat16 + (size_t)gr * 256 + c16 * 8) = *(const uint4*)(&Alds[rr * AP + c16 * 8]);
    }
}

// ---------------- per-dst softmax + weighted aggregation (bf16 gather) ----------------
// ONE wave per destination node; lane l owns channels [4l,4l+4); head h = l>>4.
// No-max softmax (scores bounded). Predicated unroll-8. Residual/bias loads
// hoisted ABOVE the gather loop so they overlap the long-latency chain.
__launch_bounds__(256)
__global__ void k_agg(const unsigned short* __restrict__ feat16, const float* __restrict__ el,
                      const float* __restrict__ er, const int* __restrict__ rowptr,
                      const int* __restrict__ ssrc,
                      const unsigned short* __restrict__ residh, const float* __restrict__ residf,
                      const float* __restrict__ bnscale, const float* __restrict__ bnshift,
                      int use_bn, const float* __restrict__ bias, int act,
                      unsigned short* __restrict__ outh, float* __restrict__ outf,
                      int final_mean) {
    int n = __builtin_amdgcn_readfirstlane(blockIdx.x * 4 + (threadIdx.x >> 6));
    int l = threadIdx.x & 63;
    int h = l >> 4;
    int beg = rowptr[n], end = rowptr[n + 1];
    float erh = er[n * 4 + h];

    // hoisted epilogue operands (issue loads early, consume after the loop)
    float4 r;
    if (residf) {
        r = *(const float4*)(residf + (size_t)n * 256 + l * 4);
    } else {
        ushort4 rv = *(const ushort4*)(residh + (size_t)n * 256 + l * 4);
        r = make_float4(bf2f(rv.x), bf2f(rv.y), bf2f(rv.z), bf2f(rv.w));
    }
    float4 sc4, sh4;
    if (use_bn) {
        sc4 = *(const float4*)(bnscale + l * 4);
        sh4 = *(const float4*)(bnshift + l * 4);
    }
    float4 bb = *(const float4*)(bias + l * 4);

    float d = 0.f;
    float4 acc = make_float4(0.f, 0.f, 0.f, 0.f);

    for (int e = beg; e < end; e += 8) {
        int ss[8];
        float cc[8];
        ushort4 ff[8];
#pragma unroll
        for (int j = 0; j < 8; j++) {
            int ee = e + j;
            ss[j] = ssrc[(ee < end) ? ee : beg];
        }
#pragma unroll
        for (int j = 0; j < 8; j++)
            cc[j] = el[ss[j] * 4 + h];
#pragma unroll
        for (int j = 0; j < 8; j++)
            ff[j] = *(const ushort4*)(feat16 + (size_t)ss[j] * 256 + l * 4);
#pragma unroll
        for (int j = 0; j < 8; j++) {
            float sc = cc[j] + erh;
            sc = (sc > 0.f) ? sc : SLOPE_A * sc;
            float wgt = ((e + j) < end) ? __expf(sc) : 0.f;
            d += wgt;
            acc.x += bf2f(ff[j].x) * wgt;
            acc.y += bf2f(ff[j].y) * wgt;
            acc.z += bf2f(ff[j].z) * wgt;
            acc.w += bf2f(ff[j].w) * wgt;
        }
    }

    float invd = 1.f / fmaxf(d, 1e-9f);
    acc.x *= invd; acc.y *= invd; acc.z *= invd; acc.w *= invd;

    if (use_bn) {
        r.x = r.x * sc4.x + sh4.x;
        r.y = r.y * sc4.y + sh4.y;
        r.z = r.z * sc4.z + sh4.z;
        r.w = r.w * sc4.w + sh4.w;
    }
    acc.x += r.x + bb.x; acc.y += r.y + bb.y;
    acc.z += r.z + bb.z; acc.w += r.w + bb.w;
    if (act) {
        acc.x = (acc.x > 0.f) ? acc.x : SLOPE_R * acc.x;
        acc.y = (acc.y > 0.f) ? acc.y : SLOPE_R * acc.y;
        acc.z = (acc.z > 0.f) ? acc.z : SLOPE_R * acc.z;
        acc.w = (acc.w > 0.f) ? acc.w : SLOPE_R * acc.w;
    }

    if (!final_mean) {
        ushort4 p;
        p.x = f2bf(acc.x); p.y = f2bf(acc.y); p.z = f2bf(acc.z); p.w = f2bf(acc.w);
        *(ushort4*)(outh + (size_t)n * 256 + l * 4) = p;
    } else {
        acc.x += __shfl_xor(acc.x, 16, 64); acc.x += __shfl_xor(acc.x, 32, 64);
        acc.y += __shfl_xor(acc.y, 16, 64); acc.y += __shfl_xor(acc.y, 32, 64);
        acc.z += __shfl_xor(acc.z, 16, 64); acc.z += __shfl_xor(acc.z, 32, 64);
        acc.w += __shfl_xor(acc.w, 16, 64); acc.w += __shfl_xor(acc.w, 32, 64);
        if (l < 16) {
            acc.x *= 0.25f; acc.y *= 0.25f; acc.z *= 0.25f; acc.w *= 0.25f;
            *(float4*)(outf + (size_t)n * 64 + l * 4) = acc;
        }
    }
}

// ---------------- BatchNorm stats: vectorized partials, no atomics (256 blocks) ----
__global__ void k_bnstats(const unsigned short* __restrict__ hh, float* __restrict__ pbuf) {
    __shared__ float ps[8 * 256];
    __shared__ float ps2[8 * 256];
    int t = threadIdx.x, b = blockIdx.x;
    int r8 = t >> 5, c32 = t & 31;
    int r0 = b * 196, r1 = min(r0 + 196, NN);
    float s[8], s2[8];
#pragma unroll
    for (int e = 0; e < 8; e++) { s[e] = 0.f; s2[e] = 0.f; }
    for (int r = r0 + r8; r < r1; r += 8) {
        uint4 v = *(const uint4*)(hh + (size_t)r * 256 + c32 * 8);
        const unsigned short* pv = (const unsigned short*)&v;
#pragma unroll
        for (int e = 0; e < 8; e++) {
            float f = bf2f(pv[e]);
            s[e] += f; s2[e] += f * f;
        }
    }
#pragma unroll
    for (int e = 0; e < 8; e++) {
        ps[r8 * 256 + c32 * 8 + e] = s[e];
        ps2[r8 * 256 + c32 * 8 + e] = s2[e];
    }
    __syncthreads();
    float ts = 0.f, ts2 = 0.f;
    for (int g = 0; g < 8; g++) { ts += ps[g * 256 + t]; ts2 += ps2[g * 256 + t]; }
    pbuf[b * 512 + t] = ts;
    pbuf[b * 512 + 256 + t] = ts2;
}

__global__ void k_bnfinal(const float* __restrict__ pbuf, const float* __restrict__ g,
                          const float* __restrict__ be, float* __restrict__ scale,
                          float* __restrict__ shift) {
    int t = threadIdx.x;
    float s = 0.f, s2 = 0.f;
    for (int b = 0; b < 256; b++) {
        s += pbuf[b * 512 + t];
        s2 += pbuf[b * 512 + 256 + t];
    }
    float mu = s * (1.f / NN);
    float var = s2 * (1.f / NN) - mu * mu;
    float rs = rsqrtf(var + 1e-5f);
    float sc = rs * g[t];
    scale[t] = sc;
    shift[t] = be[t] - mu * sc;
}

// ---------------- launcher ----------------
extern "C" void kernel_launch(void* const* d_in, const int* in_sizes, int n_in,
                              void* d_out, int out_size, void* d_ws, size_t ws_size,
                              hipStream_t stream) {
    const float* x   = (const float*)d_in[0];
    const int* src   = (const int*)d_in[1];
    const int* dst   = (const int*)d_in[2];
    const float* W1  = (const float*)d_in[3];
    const float* al1 = (const float*)d_in[4];
    const float* ar1 = (const float*)d_in[5];
    const float* b1  = (const float*)d_in[6];
    const float* W2  = (const float*)d_in[7];
    const float* al2 = (const float*)d_in[8];
    const float* ar2 = (const float*)d_in[9];
    const float* b2  = (const float*)d_in[10];
    const float* W3  = (const float*)d_in[11];
    const float* al3 = (const float*)d_in[12];
    const float* ar3 = (const float*)d_in[13];
    const float* b3  = (const float*)d_in[14];
    const float* g1  = (const float*)d_in[15];
    const float* be1 = (const float*)d_in[16];
    const float* g2  = (const float*)d_in[17];
    const float* be2 = (const float*)d_in[18];
    float* out = (float*)d_out;

    char* ws = (char*)d_ws;
    size_t off = 0;
    auto alloc = [&](size_t bytes) {
        void* p = ws + off;
        off += (bytes + 255) & ~(size_t)255;
        return p;
    };
    int* rowptr = (int*)alloc((NN + 1) * sizeof(int));
    int* cursor = (int*)alloc(NN * sizeof(int));
    int* cnt    = (int*)alloc(SCB * 256 * sizeof(int));
    int* loc    = (int*)alloc(SCB * 256 * sizeof(int));
    int* bsum   = (int*)alloc(SCB * sizeof(int));
    int* boff   = (int*)alloc(SCB * sizeof(int));
    int* ssrc   = (int*)alloc(NE * sizeof(int));
    unsigned short* feat16 = (unsigned short*)alloc((size_t)NN * 256 * sizeof(unsigned short));
    unsigned short* hbuf   = (unsigned short*)alloc((size_t)NN * 256 * sizeof(unsigned short));
    float* el   = (float*)alloc((size_t)NN * 4 * sizeof(float));
    float* er   = (float*)alloc((size_t)NN * 4 * sizeof(float));
    unsigned short* Wfrag1  = (unsigned short*)alloc(65536 * sizeof(unsigned short));
    unsigned short* Wfrag2  = (unsigned short*)alloc(65536 * sizeof(unsigned short));
    unsigned short* wlrfrag = (unsigned short*)alloc(4096 * sizeof(unsigned short));
    float* offlr   = (float*)alloc(16 * sizeof(float));
    float* cvec    = (float*)alloc(256 * sizeof(float));
    float* pbuf    = (float*)alloc(256 * 512 * sizeof(float));
    float* bnscale = (float*)alloc(256 * sizeof(float));
    float* bnshift = (float*)alloc(256 * sizeof(float));

    // CSR build (graph identical for all layers)
    hipMemsetAsync(cnt, 0, NN * sizeof(int), stream);
    k_hist<<<(NE + 255) / 256, 256, 0, stream>>>(dst, cnt);
    k_scan1<<<SCB, 256, 0, stream>>>(cnt, loc, bsum);
    k_scan2<<<1, 256, 0, stream>>>(bsum, boff, rowptr);
    k_scan3<<<SCB, 256, 0, stream>>>(loc, boff, rowptr, cursor);
    k_scatter<<<(NE + 255) / 256, 256, 0, stream>>>(src, dst, cursor, ssrc);
    k_fold<<<40, 256, 0, stream>>>(W1, nullptr, nullptr, al1, ar1,
                                   Wfrag1, nullptr, wlrfrag, offlr, 0);

    const int GB = (NN + 63) / 64;  // 782
    const int NB = NN / 4;          // 12500

    // ---- layer 1 ----
    k_gemm<<<GB, 256, 0, stream>>>(x, 1, Wfrag1, nullptr, wlrfrag, offlr, feat16, el, er);
    k_agg<<<NB, 256, 0, stream>>>(feat16, el, er, rowptr, ssrc, nullptr, x,
                                  nullptr, nullptr, 0, b1, 1, hbuf, nullptr, 0);
    k_bnstats<<<256, 256, 0, stream>>>(hbuf, pbuf);
    k_bnfinal<<<1, 256, 0, stream>>>(pbuf, g1, be1, bnscale, bnshift);
    k_fold<<<296, 256, 0, stream>>>(W2, bnscale, bnshift, al2, ar2,
                                    Wfrag2, cvec, wlrfrag, offlr, 1);

    // ---- layer 2 ----
    k_gemm<<<GB, 256, 0, stream>>>(hbuf, 0, Wfrag2, cvec, wlrfrag, offlr, feat16, el, er);
    k_agg<<<NB, 256, 0, stream>>>(feat16, el, er, rowptr, ssrc, hbuf, nullptr,
                                  bnscale, bnshift, 1, b2, 1, hbuf, nullptr, 0);
    k_bnstats<<<256, 256, 0, stream>>>(hbuf, pbuf);
    k_bnfinal<<<1, 256, 0, stream>>>(pbuf, g2, be2, bnscale, bnshift);
    k_fold<<<296, 256, 0, stream>>>(W3, bnscale, bnshift, al3, ar3,
                                    Wfrag2, cvec, wlrfrag, offlr, 1);

    // ---- layer 3 ----
    k_gemm<<<GB, 256, 0, stream>>>(hbuf, 0, Wfrag2, cvec, wlrfrag, offlr, feat16, el, er);
    k_agg<<<NB, 256, 0, stream>>>(feat16, el, er, rowptr, ssrc, hbuf, nullptr,
                                  bnscale, bnshift, 1, b3, 0, nullptr, out, 1);
}